// Round 4
// baseline (82.268 us; speedup 1.0000x reference)
//
#include <hip/hip_runtime.h>

#define B_SZ 16
#define N_BOX 2048
#define AH 256
#define AW 256
#define ROWS 8            // rows per block in main kernel -> 32 strips/batch

// ---------------------------------------------------------------------------
// Kernel 1: rasterize boxes -> integer rects (plain stores into d_ws, no init
// needed), build sorted-batch range table, zero the output accumulator.
// ---------------------------------------------------------------------------
__global__ __launch_bounds__(256) void prep_kernel(
    const float* __restrict__ target,   // [N_BOX, 6]
    const int*   __restrict__ img_h_p,  // scalar
    const int*   __restrict__ img_w_p,  // scalar
    int4*        __restrict__ rects,    // [N_BOX] (X1,Y1,X2,Y2); empty if invalid
    int*         __restrict__ starts,   // [B_SZ+1]
    float*       __restrict__ out)      // [1]
{
    int i = blockIdx.x * blockDim.x + threadIdx.x;
    if (i == 0) out[0] = 0.0f;   // harness re-poisons d_out to 0xAA each call
    if (i >= N_BOX) return;

    float fh = (float)img_h_p[0];
    float fw = (float)img_w_p[0];

    const float* t = target + (size_t)i * 6;
    float xc = t[2], yc = t[3], bw = t[4], bh = t[5];

    // exact replication of reference float32 math
    float x1 = fw * (xc - bw * 0.5f);
    float y1 = fh * (yc - bh * 0.5f);
    float x2 = fw * (xc + bw * 0.5f);
    float y2 = fh * (yc + bh * 0.5f);

    bool valid = (x1 <= fw) && (y1 <= fh) && (x2 <= fw) && (y2 <= fh);

    float sx = (float)AW / fw;
    float sy = (float)AH / fh;

    int X1 = (int)fmaxf(truncf(x1 * sx), 0.0f);
    int Y1 = (int)fmaxf(truncf(y1 * sy), 0.0f);
    int X2 = (int)fminf(ceilf(x2 * sx) + 1.0f, (float)AW);
    int Y2 = (int)fminf(ceilf(y2 * sy) + 1.0f, (float)AH);

    if (!valid) { X1 = 0; X2 = 0; Y1 = 0; Y2 = 0; }  // empty rect
    rects[i] = make_int4(X1, Y1, X2, Y2);

    // bidx is sorted; thread i owns boundary entries (prev_b, b]
    int b  = (int)t[0];
    int bp = (i == 0) ? -1 : (int)target[(size_t)(i - 1) * 6];
    for (int k = bp + 1; k <= b; ++k) starts[k] = i;
    if (i == N_BOX - 1)
        for (int k = b + 1; k <= B_SZ; ++k) starts[k] = N_BOX;
}

// ---------------------------------------------------------------------------
// Kernel 2: one block per (batch, 8-row strip). Box loop reads rects with a
// wave-uniform index -> batched scalar loads + scalar y-reject branch;
// per-thread work ~4 VALU per accepted box. In-register 8-bit coverage,
// fused BCE + block reduction, one gated atomicAdd per block.
// ---------------------------------------------------------------------------
__global__ __launch_bounds__(256) void main_kernel(
    const float* __restrict__ mask,    // [B_SZ,1,AH,AW]
    const int4*  __restrict__ rects,
    const int*   __restrict__ starts,
    float*       __restrict__ out)
{
    const int b  = blockIdx.y;
    const int y0 = blockIdx.x * ROWS;
    const int x  = threadIdx.x;

    __shared__ float s_red[4];

    const int s   = starts[b];
    const int e   = starts[b + 1];
    const int cnt = e - s;

    unsigned cov = 0;                  // bit r: pixel (y0+r, x) covered
    for (int j = s; j < e; ++j) {
        const int4 r = rects[j];       // uniform index -> s_load_dwordx4
        // scalar y-reject: does [r.y, r.w) intersect [y0, y0+ROWS)?
        if (r.y < y0 + ROWS && r.w > y0) {
            const int lo = max(r.y - y0, 0);
            const int hi = min(r.w - y0, ROWS);
            const unsigned rowbits = ((1u << (hi - lo)) - 1u) << lo; // SALU
            const bool xin = (x >= r.x) && (x < r.z);
            cov |= xin ? rowbits : 0u; // v_cndmask + v_or
        }
    }

    float acc = 0.0f;
    #pragma unroll
    for (int r = 0; r < ROWS; ++r) {
        const float l = mask[((size_t)b * AH + (y0 + r)) * AW + x];
        const float m = (float)((cov >> r) & 1u);
        acc += fmaxf(l, 0.0f) - l * m + log1pf(expf(-fabsf(l)));
    }

    // wave (64-lane) shuffle reduction, then cross-wave via LDS
    #pragma unroll
    for (int off = 32; off > 0; off >>= 1) acc += __shfl_down(acc, off, 64);
    const int wave = x >> 6;
    if ((x & 63) == 0) s_red[wave] = acc;
    __syncthreads();
    if (x == 0) {
        const float sum = s_red[0] + s_red[1] + s_red[2] + s_red[3];
        if (cnt > 0)   // has_box gate
            atomicAdd(out, sum * (1.0f / (float)(AH * AW)));
    }
}

extern "C" void kernel_launch(void* const* d_in, const int* in_sizes, int n_in,
                              void* d_out, int out_size, void* d_ws, size_t ws_size,
                              hipStream_t stream) {
    const float* attention_mask = (const float*)d_in[0];
    const float* target         = (const float*)d_in[1];
    const int*   img_h          = (const int*)d_in[3];
    const int*   img_w          = (const int*)d_in[4];

    int4* rects  = (int4*)d_ws;
    int*  starts = (int*)((char*)d_ws + (size_t)N_BOX * sizeof(int4));
    float* out   = (float*)d_out;

    prep_kernel<<<(N_BOX + 255) / 256, 256, 0, stream>>>(
        target, img_h, img_w, rects, starts, out);

    dim3 grid(AH / ROWS, B_SZ);
    main_kernel<<<grid, 256, 0, stream>>>(attention_mask, rects, starts, out);
}

// Round 5
// 74.392 us; speedup vs baseline: 1.1059x; 1.1059x over previous
//
#include <hip/hip_runtime.h>

#define B_SZ 16
#define N_BOX 2048
#define AH 256
#define AW 256
#define ROWS 8                 // rows per block -> 32 strips/batch, 512 blocks

// ---------------------------------------------------------------------------
// Single fused kernel. Block = (batch b, 8-row strip). All 2048 boxes are
// processed thread-parallel in 8 chunks of 256: per-thread rect math (exact
// replication of the jnp float32 reference), filter bidx==b && y-intersect,
// compact survivors (~21/strip) into an LDS list. One barrier, then a short
// LDS-broadcast OR loop builds per-column coverage bits; fused BCE over the
// strip's 8 coalesced rows; block reduction; one gated atomicAdd into out
// (out zeroed by a 4-byte memset node before this kernel).
// ---------------------------------------------------------------------------
__global__ __launch_bounds__(256) void fused_kernel(
    const float* __restrict__ target,   // [N_BOX, 6]
    const float* __restrict__ mask,     // [B_SZ,1,AH,AW]
    const int*   __restrict__ img_h_p,
    const int*   __restrict__ img_w_p,
    float*       __restrict__ out)      // [1], pre-zeroed via memset node
{
    const int b  = blockIdx.x >> 5;            // 32 strips per batch
    const int y0 = (blockIdx.x & 31) * ROWS;
    const int x  = threadIdx.x;

    __shared__ unsigned s_list[N_BOX];         // packed (X1, X2, rowbits)
    __shared__ int   s_n;
    __shared__ int   s_has;
    __shared__ float s_red[4];

    if (x == 0) { s_n = 0; s_has = 0; }
    __syncthreads();

    const float fh = (float)img_h_p[0];
    const float fw = (float)img_w_p[0];
    const float sx = (float)AW / fw;
    const float sy = (float)AH / fh;

    for (int base = 0; base < N_BOX; base += 256) {
        const float* t = target + (size_t)(base + x) * 6;
        const int bi = (int)t[0];
        if (bi == b) {
            s_has = 1;                          // all writers store 1: race-free
            const float xc = t[2], yc = t[3], bw = t[4], bh = t[5];
            // exact replication of reference float32 math
            const float x1 = fw * (xc - bw * 0.5f);
            const float y1 = fh * (yc - bh * 0.5f);
            const float x2 = fw * (xc + bw * 0.5f);
            const float y2 = fh * (yc + bh * 0.5f);
            const bool valid = (x1 <= fw) && (y1 <= fh) &&
                               (x2 <= fw) && (y2 <= fh);
            const int X1 = (int)fmaxf(truncf(x1 * sx), 0.0f);
            const int Y1 = (int)fmaxf(truncf(y1 * sy), 0.0f);
            const int X2 = (int)fminf(ceilf(x2 * sx) + 1.0f, (float)AW);
            const int Y2 = (int)fminf(ceilf(y2 * sy) + 1.0f, (float)AH);
            if (valid && X1 < X2 && Y1 < y0 + ROWS && Y2 > y0) {
                const int lo = max(Y1 - y0, 0);
                const int hi = min(Y2 - y0, ROWS);
                const unsigned rowbits = ((1u << (hi - lo)) - 1u) << lo;
                const unsigned entry = (unsigned)X1 | ((unsigned)X2 << 9)
                                     | (rowbits << 18);
                s_list[atomicAdd(&s_n, 1)] = entry;
            }
        }
    }
    __syncthreads();

    // coverage OR over the compacted list (order-independent -> deterministic)
    const int n = s_n;
    unsigned cov = 0;                           // bit r: pixel (y0+r, x)
    for (int j = 0; j < n; ++j) {
        const unsigned e = s_list[j];           // LDS broadcast (same addr)
        const int X1 = (int)(e & 511u);
        const int X2 = (int)((e >> 9) & 511u);
        cov |= (x >= X1 && x < X2) ? (e >> 18) : 0u;
    }

    float acc = 0.0f;
    #pragma unroll
    for (int r = 0; r < ROWS; ++r) {
        const float l = mask[((size_t)b * AH + (y0 + r)) * AW + x];
        const float m = (float)((cov >> r) & 1u);
        acc += fmaxf(l, 0.0f) - l * m + log1pf(expf(-fabsf(l)));
    }

    // wave (64-lane) shuffle reduction, then cross-wave via LDS
    #pragma unroll
    for (int off = 32; off > 0; off >>= 1) acc += __shfl_down(acc, off, 64);
    if ((x & 63) == 0) s_red[x >> 6] = acc;
    __syncthreads();
    if (x == 0 && s_has) {
        const float sum = s_red[0] + s_red[1] + s_red[2] + s_red[3];
        atomicAdd(out, sum * (1.0f / (float)(AH * AW)));
    }
}

extern "C" void kernel_launch(void* const* d_in, const int* in_sizes, int n_in,
                              void* d_out, int out_size, void* d_ws, size_t ws_size,
                              hipStream_t stream) {
    const float* attention_mask = (const float*)d_in[0];
    const float* target         = (const float*)d_in[1];
    const int*   img_h          = (const int*)d_in[3];
    const int*   img_w          = (const int*)d_in[4];
    float*       out            = (float*)d_out;

    hipMemsetAsync(out, 0, sizeof(float), stream);   // zero accumulator

    fused_kernel<<<B_SZ * (AH / ROWS), 256, 0, stream>>>(
        target, attention_mask, img_h, img_w, out);
}